// Round 6
// 1225.000 us; speedup vs baseline: 1.0700x; 1.0700x over previous
//
#include <hip/hip_runtime.h>
#include <hip/hip_bf16.h>
#include <math.h>
#include <stdint.h>

typedef __hip_bfloat16 bf16_t;
typedef __bf16 bf16x8 __attribute__((ext_vector_type(8)));
typedef float f32x4 __attribute__((ext_vector_type(4)));

#define MFMA_BF16(a, b, c) __builtin_amdgcn_mfma_f32_16x16x32_bf16((a), (b), (c), 0, 0, 0)

// Load 8 consecutive f32 and pack to 8 bf16 (one uint4 for ds_write b128).
__device__ __forceinline__ uint4 ld8_f32_bf16(const float* p) {
  const float4 x = *(const float4*)p;
  const float4 y = *(const float4*)(p + 4);
  union { bf16_t h[8]; uint4 u; } r;
  r.h[0] = __float2bfloat16(x.x); r.h[1] = __float2bfloat16(x.y);
  r.h[2] = __float2bfloat16(x.z); r.h[3] = __float2bfloat16(x.w);
  r.h[4] = __float2bfloat16(y.x); r.h[5] = __float2bfloat16(y.y);
  r.h[6] = __float2bfloat16(y.z); r.h[7] = __float2bfloat16(y.w);
  return r.u;
}

__device__ __forceinline__ uint4 pack8_bf16(const float4 x, const float4 y) {
  union { bf16_t h[8]; uint4 u; } r;
  r.h[0] = __float2bfloat16(x.x); r.h[1] = __float2bfloat16(x.y);
  r.h[2] = __float2bfloat16(x.z); r.h[3] = __float2bfloat16(x.w);
  r.h[4] = __float2bfloat16(y.x); r.h[5] = __float2bfloat16(y.y);
  r.h[6] = __float2bfloat16(y.z); r.h[7] = __float2bfloat16(y.w);
  return r.u;
}

// Async global->LDS, 16B per lane. LDS dest is wave-uniform base + lane*16.
__device__ __forceinline__ void gload16(const bf16_t* g, bf16_t* lds) {
  __builtin_amdgcn_global_load_lds(
      (const __attribute__((address_space(1))) void*)g,
      (__attribute__((address_space(3))) void*)lds, 16, 0, 0);
}

// Convert 6 weight matrices (512x512 f32, row-major [out][in]) to bf16.
// grid (128, 6), 256 threads, 8 elems/thread.
__global__ __launch_bounds__(256) void cvt_w6(const float* __restrict__ W0,
                                              const float* __restrict__ W1,
                                              const float* __restrict__ W2,
                                              const float* __restrict__ W3,
                                              const float* __restrict__ W4,
                                              const float* __restrict__ W5,
                                              bf16_t* __restrict__ dst) {
  const int m = blockIdx.y;
  const float* src = W0;
  if (m == 1) src = W1;
  else if (m == 2) src = W2;
  else if (m == 3) src = W3;
  else if (m == 4) src = W4;
  else if (m == 5) src = W5;
  const size_t i = ((size_t)blockIdx.x * 256 + threadIdx.x) * 8;
  *(uint4*)&dst[(size_t)m * 262144 + i] = ld8_f32_bf16(&src[i]);
}

// C[m,n] = (sum_k A[m,k]*W[n,k] + bias[n]) * alpha.  A f32; W bf16 (pre-converted);
// bias f32; C bf16.  128x128 tile, BK=32, 256 threads = 4 waves (2x2 of 64x64).
// W staged via global_load_lds; A converted in regs with next-iter prefetch
// issued during the MFMA phase (latency hides under compute).
__global__ __launch_bounds__(256) void gemm_aw(const float* __restrict__ A,
                                               const bf16_t* __restrict__ W,
                                               const float* __restrict__ bias,
                                               bf16_t* __restrict__ C, float alpha) {
  const int K = 512, N = 512;
  __shared__ __align__(16) bf16_t As[128 * 32];
  __shared__ __align__(16) bf16_t Bs[128 * 32];
  const int tid = threadIdx.x;
  const int w = tid >> 6, lane = tid & 63;
  const int quad = lane >> 4, l16 = lane & 15;
  const int wm = (w >> 1) * 64, wn = (w & 1) * 64;
  const size_t m0 = (size_t)blockIdx.x * 128;
  const int n0 = blockIdx.y * 128;
  const float* Ab = A + m0 * K;
  const bf16_t* Wb = W + (size_t)n0 * K;
  const int r0 = tid >> 2;          // staging row (0..63)
  const int c0 = (tid & 3) * 8;     // staging col group (8 elems)
  f32x4 acc[4][4] = {};
  // prefetch A for k0=0
  float4 pa0 = *(const float4*)&Ab[(size_t)r0 * K + c0];
  float4 pa1 = *(const float4*)&Ab[(size_t)r0 * K + c0 + 4];
  float4 pa2 = *(const float4*)&Ab[(size_t)(r0 + 64) * K + c0];
  float4 pa3 = *(const float4*)&Ab[(size_t)(r0 + 64) * K + c0 + 4];
  for (int k0 = 0; k0 < K; k0 += 32) {
    const uint4 a0 = pack8_bf16(pa0, pa1);
    const uint4 a1 = pack8_bf16(pa2, pa3);
    __syncthreads();  // prior iteration's LDS reads complete
    gload16(&Wb[(size_t)r0 * K + k0 + c0], &Bs[w * 512]);
    gload16(&Wb[(size_t)(r0 + 64) * K + k0 + c0], &Bs[2048 + w * 512]);
    *(uint4*)&As[r0 * 32 + c0] = a0;
    *(uint4*)&As[(r0 + 64) * 32 + c0] = a1;
    __syncthreads();  // barrier drains vmcnt: gload data landed
    bf16x8 af[4], bfr[4];
#pragma unroll
    for (int i = 0; i < 4; i++)
      af[i] = *(const bf16x8*)&As[(wm + i * 16 + l16) * 32 + quad * 8];
#pragma unroll
    for (int j = 0; j < 4; j++)
      bfr[j] = *(const bf16x8*)&Bs[(wn + j * 16 + l16) * 32 + quad * 8];
    if (k0 + 32 < K) {  // issue next-iter A loads; overlap with MFMA below
      pa0 = *(const float4*)&Ab[(size_t)r0 * K + k0 + 32 + c0];
      pa1 = *(const float4*)&Ab[(size_t)r0 * K + k0 + 32 + c0 + 4];
      pa2 = *(const float4*)&Ab[(size_t)(r0 + 64) * K + k0 + 32 + c0];
      pa3 = *(const float4*)&Ab[(size_t)(r0 + 64) * K + k0 + 32 + c0 + 4];
    }
#pragma unroll
    for (int i = 0; i < 4; i++)
#pragma unroll
      for (int j = 0; j < 4; j++)
        acc[i][j] = MFMA_BF16(af[i], bfr[j], acc[i][j]);
  }
#pragma unroll
  for (int j = 0; j < 4; j++) {
    const int col = n0 + wn + j * 16 + l16;
    const float bv = bias[col];
#pragma unroll
    for (int i = 0; i < 4; i++) {
      const size_t row = m0 + wm + i * 16 + quad * 4;
#pragma unroll
      for (int v = 0; v < 4; v++) {
        const float x = (acc[i][j][v] + bv) * alpha;
        C[(row + v) * N + col] = __float2bfloat16(x);
      }
    }
  }
}

// A bf16, W bf16 — both via global_load_lds (the verified m97 structure). C bf16.
__global__ __launch_bounds__(256) void gemm_bb(const bf16_t* __restrict__ A,
                                               const bf16_t* __restrict__ W,
                                               const float* __restrict__ bias,
                                               bf16_t* __restrict__ C) {
  const int K = 512, N = 512;
  __shared__ __align__(16) bf16_t As[128 * 32];
  __shared__ __align__(16) bf16_t Bs[128 * 32];
  const int tid = threadIdx.x;
  const int w = tid >> 6, lane = tid & 63;
  const int quad = lane >> 4, l16 = lane & 15;
  const int wm = (w >> 1) * 64, wn = (w & 1) * 64;
  const size_t m0 = (size_t)blockIdx.x * 128;
  const int n0 = blockIdx.y * 128;
  const bf16_t* Ab = A + m0 * K;
  const bf16_t* Wb = W + (size_t)n0 * K;
  const int r0 = tid >> 2;
  const int c0 = (tid & 3) * 8;
  f32x4 acc[4][4] = {};
  for (int k0 = 0; k0 < K; k0 += 32) {
    __syncthreads();  // prior iteration's LDS reads complete
    gload16(&Ab[(size_t)r0 * K + k0 + c0], &As[w * 512]);
    gload16(&Ab[(size_t)(r0 + 64) * K + k0 + c0], &As[2048 + w * 512]);
    gload16(&Wb[(size_t)r0 * K + k0 + c0], &Bs[w * 512]);
    gload16(&Wb[(size_t)(r0 + 64) * K + k0 + c0], &Bs[2048 + w * 512]);
    __syncthreads();  // barrier drains vmcnt: data landed
    bf16x8 af[4], bfr[4];
#pragma unroll
    for (int i = 0; i < 4; i++)
      af[i] = *(const bf16x8*)&As[(wm + i * 16 + l16) * 32 + quad * 8];
#pragma unroll
    for (int j = 0; j < 4; j++)
      bfr[j] = *(const bf16x8*)&Bs[(wn + j * 16 + l16) * 32 + quad * 8];
#pragma unroll
    for (int i = 0; i < 4; i++)
#pragma unroll
      for (int j = 0; j < 4; j++)
        acc[i][j] = MFMA_BF16(af[i], bfr[j], acc[i][j]);
  }
#pragma unroll
  for (int j = 0; j < 4; j++) {
    const int col = n0 + wn + j * 16 + l16;
    const float bv = bias[col];
#pragma unroll
    for (int i = 0; i < 4; i++) {
      const size_t row = m0 + wm + i * 16 + quad * 4;
#pragma unroll
      for (int v = 0; v < 4; v++) {
        const float x = acc[i][j][v] + bv;
        C[(row + v) * N + col] = __float2bfloat16(x);
      }
    }
  }
}

// Gating: out = tanh(A@Wi^T + bi) * sigmoid(A@Wg^T + bg).
// A bf16, Wi/Wg bf16 (pre-converted) — all via global_load_lds; out f32.
__global__ __launch_bounds__(256) void gemm_gate2(const bf16_t* __restrict__ A,
                                                  const bf16_t* __restrict__ Wi,
                                                  const float* __restrict__ bi,
                                                  const bf16_t* __restrict__ Wg,
                                                  const float* __restrict__ bg,
                                                  float* __restrict__ C) {
  const int K = 512, N = 512;
  __shared__ __align__(16) bf16_t As[128 * 32];
  __shared__ __align__(16) bf16_t Bi[128 * 32];
  __shared__ __align__(16) bf16_t Bg[128 * 32];
  const int tid = threadIdx.x;
  const int w = tid >> 6, lane = tid & 63;
  const int quad = lane >> 4, l16 = lane & 15;
  const int wm = (w >> 1) * 64, wn = (w & 1) * 64;
  const size_t m0 = (size_t)blockIdx.x * 128;
  const int n0 = blockIdx.y * 128;
  const bf16_t* Ab = A + m0 * K;
  const bf16_t* Wib = Wi + (size_t)n0 * K;
  const bf16_t* Wgb = Wg + (size_t)n0 * K;
  const int r0 = tid >> 2;
  const int c0 = (tid & 3) * 8;
  f32x4 ai[4][4] = {};
  f32x4 ag[4][4] = {};
  for (int k0 = 0; k0 < K; k0 += 32) {
    __syncthreads();
    gload16(&Ab[(size_t)r0 * K + k0 + c0], &As[w * 512]);
    gload16(&Ab[(size_t)(r0 + 64) * K + k0 + c0], &As[2048 + w * 512]);
    gload16(&Wib[(size_t)r0 * K + k0 + c0], &Bi[w * 512]);
    gload16(&Wib[(size_t)(r0 + 64) * K + k0 + c0], &Bi[2048 + w * 512]);
    gload16(&Wgb[(size_t)r0 * K + k0 + c0], &Bg[w * 512]);
    gload16(&Wgb[(size_t)(r0 + 64) * K + k0 + c0], &Bg[2048 + w * 512]);
    __syncthreads();
    bf16x8 af[4], bif[4], bgf[4];
#pragma unroll
    for (int i = 0; i < 4; i++)
      af[i] = *(const bf16x8*)&As[(wm + i * 16 + l16) * 32 + quad * 8];
#pragma unroll
    for (int j = 0; j < 4; j++) {
      bif[j] = *(const bf16x8*)&Bi[(wn + j * 16 + l16) * 32 + quad * 8];
      bgf[j] = *(const bf16x8*)&Bg[(wn + j * 16 + l16) * 32 + quad * 8];
    }
#pragma unroll
    for (int i = 0; i < 4; i++)
#pragma unroll
      for (int j = 0; j < 4; j++) {
        ai[i][j] = MFMA_BF16(af[i], bif[j], ai[i][j]);
        ag[i][j] = MFMA_BF16(af[i], bgf[j], ag[i][j]);
      }
  }
#pragma unroll
  for (int j = 0; j < 4; j++) {
    const int col = n0 + wn + j * 16 + l16;
    const float bvi = bi[col];
    const float bvg = bg[col];
#pragma unroll
    for (int i = 0; i < 4; i++) {
      const size_t row = m0 + wm + i * 16 + quad * 4;
#pragma unroll
      for (int v = 0; v < 4; v++) {
        const float xi = ai[i][j][v] + bvi;
        const float xg = ag[i][j][v] + bvg;
        C[(row + v) * N + col] = tanhf(xi) * (1.0f / (1.0f + __expf(-xg)));
      }
    }
  }
}

// Per-(b,h) attention: one wave does a full 64x64x64 head (bf16 ws tensors).
// O may alias Qh: per-block regions are disjoint; Q fully staged to LDS before stores.
__global__ __launch_bounds__(64) void attn_head(const bf16_t* Qh,
                                                const bf16_t* Kh,
                                                const bf16_t* Vh,
                                                bf16_t* O,
                                                const int* __restrict__ seq_mask) {
  const int B = 1280, D = 512;
  const int b = blockIdx.x >> 3, h = blockIdx.x & 7;
  const int lane = threadIdx.x;
  __shared__ __align__(16) bf16_t Qs[64 * 64];
  __shared__ __align__(16) bf16_t Ks[64 * 64];
  __shared__ __align__(16) bf16_t VT[64 * 64];  // V transposed: VT[d][k]
  bf16_t* Ps = Qs;                              // reuse Q tile for P
  const size_t cb = (size_t)h * 64;
  for (int idx = lane; idx < 512; idx += 64) {
    const int r = idx >> 3, cg = (idx & 7) << 3;
    const size_t go = (size_t)(r * B + b) * D + cb + cg;
    *(uint4*)&Qs[r * 64 + cg] = *(const uint4*)&Qh[go];
    *(uint4*)&Ks[r * 64 + cg] = *(const uint4*)&Kh[go];
    uint4 vv = *(const uint4*)&Vh[go];
    const bf16_t* vp = (const bf16_t*)&vv;
#pragma unroll
    for (int jj = 0; jj < 8; jj++) VT[(cg + jj) * 64 + r] = vp[jj];
  }
  __syncthreads();
  const int quad = lane >> 4, l16 = lane & 15;
  f32x4 sc[4][4] = {};
#pragma unroll
  for (int ks = 0; ks < 2; ks++) {
    bf16x8 qa[4], kb[4];
#pragma unroll
    for (int i = 0; i < 4; i++)
      qa[i] = *(const bf16x8*)&Qs[(i * 16 + l16) * 64 + ks * 32 + quad * 8];
#pragma unroll
    for (int j = 0; j < 4; j++)
      kb[j] = *(const bf16x8*)&Ks[(j * 16 + l16) * 64 + ks * 32 + quad * 8];
#pragma unroll
    for (int i = 0; i < 4; i++)
#pragma unroll
      for (int j = 0; j < 4; j++)
        sc[i][j] = MFMA_BF16(qa[i], kb[j], sc[i][j]);
  }
  const bool causal = (seq_mask[0] != 0);
  __syncthreads();  // done reading Qs; about to overwrite with P
  // softmax per row; C-layout: row = i*16 + quad*4 + v, col = j*16 + l16
#pragma unroll
  for (int i = 0; i < 4; i++) {
#pragma unroll
    for (int v = 0; v < 4; v++) {
      const int r = i * 16 + quad * 4 + v;
      float sv[4];
      float mx = -3e38f;
#pragma unroll
      for (int j = 0; j < 4; j++) {
        const int c = j * 16 + l16;
        float s = sc[i][j][v];
        if (causal && c > r) s = -3e38f;
        sv[j] = s;
        mx = fmaxf(mx, s);
      }
#pragma unroll
      for (int m = 1; m < 16; m <<= 1) mx = fmaxf(mx, __shfl_xor(mx, m, 16));
      float sum = 0.f;
#pragma unroll
      for (int j = 0; j < 4; j++) {
        const float e = (sv[j] <= -1e38f) ? 0.f : __expf(sv[j] - mx);
        sv[j] = e;
        sum += e;
      }
#pragma unroll
      for (int m = 1; m < 16; m <<= 1) sum += __shfl_xor(sum, m, 16);
      const float inv = 1.0f / sum;
#pragma unroll
      for (int j = 0; j < 4; j++)
        Ps[r * 64 + j * 16 + l16] = __float2bfloat16(sv[j] * inv);
    }
  }
  __syncthreads();
  f32x4 oc[4][4] = {};
#pragma unroll
  for (int ks = 0; ks < 2; ks++) {
    bf16x8 pf[4], vf[4];
#pragma unroll
    for (int i = 0; i < 4; i++)
      pf[i] = *(const bf16x8*)&Ps[(i * 16 + l16) * 64 + ks * 32 + quad * 8];
#pragma unroll
    for (int j = 0; j < 4; j++)
      vf[j] = *(const bf16x8*)&VT[(j * 16 + l16) * 64 + ks * 32 + quad * 8];
#pragma unroll
    for (int i = 0; i < 4; i++)
#pragma unroll
      for (int j = 0; j < 4; j++)
        oc[i][j] = MFMA_BF16(pf[i], vf[j], oc[i][j]);
  }
#pragma unroll
  for (int i = 0; i < 4; i++)
#pragma unroll
    for (int j = 0; j < 4; j++) {
      const int c = j * 16 + l16;
#pragma unroll
      for (int v = 0; v < 4; v++) {
        const int r = i * 16 + quad * 4 + v;
        O[(size_t)(r * B + b) * D + cb + c] = __float2bfloat16(oc[i][j][v]);
      }
    }
}

extern "C" void kernel_launch(void* const* d_in, const int* in_sizes, int n_in,
                              void* d_out, int out_size, void* d_ws, size_t ws_size,
                              hipStream_t stream) {
  const float* query = (const float*)d_in[0];
  const float* key_ = (const float*)d_in[1];
  const float* value = (const float*)d_in[2];
  // d_in[3] = attn_mask: unused by the reference (it builds tmask from seq_mask)
  const float* Wq = (const float*)d_in[4];
  const float* bq = (const float*)d_in[5];
  const float* Wk = (const float*)d_in[6];
  const float* bk = (const float*)d_in[7];
  const float* Wv = (const float*)d_in[8];
  const float* bv = (const float*)d_in[9];
  const float* Wo = (const float*)d_in[10];
  const float* bo = (const float*)d_in[11];
  const float* Wti = (const float*)d_in[12];
  const float* bti = (const float*)d_in[13];
  const float* Wtg = (const float*)d_in[14];
  const float* btg = (const float*)d_in[15];
  const int* seq_mask = (const int*)d_in[16];
  float* out = (float*)d_out;

  const size_t M = 81920;  // L * A * S = 64*64*20
  const size_t buf = M * 512;
  const size_t wsz = 512 * 512;  // one weight matrix, elems
  bf16_t* Qh = (bf16_t*)d_ws;
  bf16_t* Kh = Qh + buf;
  bf16_t* Vh = Kh + buf;
  bf16_t* Wbase = Vh + buf;  // 6 x 512KB bf16 weights = 3 MiB (ws >= 240 MiB already in use)
  bf16_t* Wqb = Wbase + 0 * wsz;
  bf16_t* Wkb = Wbase + 1 * wsz;
  bf16_t* Wvb = Wbase + 2 * wsz;
  bf16_t* Wob = Wbase + 3 * wsz;
  bf16_t* Wtib = Wbase + 4 * wsz;
  bf16_t* Wtgb = Wbase + 5 * wsz;
  bf16_t* Ob = Qh;  // attention output aliases Qh (per-block disjoint r/w)
  bf16_t* Ta = Kh;  // t_attn overwrites Kh (dead after attention)

  dim3 gg(640, 4), gb(256);
  hipLaunchKernelGGL(cvt_w6, dim3(128, 6), gb, 0, stream, Wq, Wk, Wv, Wo, Wti, Wtg, Wbase);
  hipLaunchKernelGGL(gemm_aw, gg, gb, 0, stream, query, Wqb, bq, Qh, 0.125f);
  hipLaunchKernelGGL(gemm_aw, gg, gb, 0, stream, key_, Wkb, bk, Kh, 1.0f);
  hipLaunchKernelGGL(gemm_aw, gg, gb, 0, stream, value, Wvb, bv, Vh, 1.0f);
  hipLaunchKernelGGL(attn_head, dim3(10240), dim3(64), 0, stream, Qh, Kh, Vh, Ob, seq_mask);
  hipLaunchKernelGGL(gemm_bb, gg, gb, 0, stream, Ob, Wob, bo, Ta);
  hipLaunchKernelGGL(gemm_gate2, gg, gb, 0, stream, Ta, Wtib, bti, Wtgb, btg, out);
}